// Round 7
// baseline (347.666 us; speedup 1.0000x reference)
//
#include <hip/hip_runtime.h>

// BasicRNN R17: full steps = fat-wave partial (k_partW) + proven 4-slice reduce
// (k_red2). Unified model from R12-R16: step time = per-CU VMEM instr count x
// ~61cyc per 1KB flat-load instr (R12=R14 26us @1024 instr/CU regardless of wave
// count; R15 scaled with instrs; gload_lds ~2x worse per instr -> flat loads only).
// Lever: per-wave 128x128 output tile (16x f32x16 = 256 acc VGPR, 1 wave/SIMD via
// __launch_bounds__(256,1) -- occupancy irrelevant under CU-shared pipe cap):
// 8 loads per 16 MFMA halves operand instrs -> 512 load-instr/CU ~13us vs 26.
// Grid 256 x 256thr (4 waves), wave K=256, k-split 16 folded to 4 by epilogue-only
// LDS reduce (barriers AFTER all loads done -> no R13 drain trap), then k_red2
// (R13/R15-verified: 4 f32 slices + gate*E + relu + bf16 swizzle).
// t=1 (k_step3<64>), t=9 (part9/red9 quarter-work), prep, out unchanged from R14.
// Fragment-tiled operands:
//   elem(r,c) = frag*512 + lane*8 + (c&7), frag=(r>>5)*(C/16)+(c>>4), lane=(r&31)+32*((c>>3)&1)

typedef __bf16 bf16x8 __attribute__((ext_vector_type(8)));
typedef float  f32x16 __attribute__((ext_vector_type(16)));

#define TOTAL 4096
#define BATCH 256
#define INDIM 2048
#define SDIM  1024
#define NCLS  1000

#define MFMA(a, b, c) __builtin_amdgcn_mfma_f32_32x32x16_bf16((a), (b), (c), 0, 0, 0)

__device__ inline f32x16 zero16() {
    f32x16 v;
#pragma unroll
    for (int i = 0; i < 16; ++i) v[i] = 0.f;
    return v;
}

__device__ inline void swz_slot(const float* __restrict__ in, __bf16* __restrict__ out,
                                int C, int Rvalid, int t) {
    const int lane = t & 63;
    const int frag = t >> 6;
    const int kcN = C >> 4;
    const int rt = frag / kcN;
    const int kc = frag - rt * kcN;
    const int r = rt * 32 + (lane & 31);
    const int c = kc * 16 + (lane >> 5) * 8;
    alignas(16) __bf16 v[8];
    if (r < Rvalid) {
        const float* p = in + (size_t)r * C + c;
#pragma unroll
        for (int j = 0; j < 8; ++j) v[j] = (__bf16)p[j];
    } else {
#pragma unroll
        for (int j = 0; j < 8; ++j) v[j] = (__bf16)0.f;
    }
    *(ulonglong2*)(out + (size_t)t * 8) = *(const ulonglong2*)v;
}

// ---- merged preprocessing + E-GEMM ----
// grid 2816 x 256: [0,256) E-GEMM; [256,2304) W transpose-swizzle (16k x 512n tiles);
//                  [2304,2816) out_w swizzle
__global__ __launch_bounds__(256) void k_prep(const float* __restrict__ W,
                                              const float* __restrict__ x,
                                              const float* __restrict__ in_w,
                                              const float* __restrict__ in_b,
                                              const float* __restrict__ out_w,
                                              __bf16* __restrict__ WT,
                                              __bf16* __restrict__ OWT,
                                              float* __restrict__ Ebuf,
                                              __bf16* __restrict__ H0) {
    __shared__ float t[16 * 512];   // 32 KB; E path reuses first 4x1024 as reduce buf
    const int bid = blockIdx.x;
    const int tid = threadIdx.x;
    if (bid < 256) {
        // ---- E = x @ in_w^T + in_b ; H0[:, :1024] = relu(E) (tiled) ----
        float* red = t;   // 4 x 1024
        const int mt = bid >> 5, nt = bid & 31;
        const int wave = tid >> 6, lane = tid & 63;
        const int l31 = lane & 31, kh = (lane >> 5) * 8;
        const int k0 = wave * 512;
        const float* Ax = x    + (size_t)(mt * 32 + l31) * INDIM + k0 + kh;
        const float* Bw = in_w + (size_t)(nt * 32 + l31) * INDIM + k0 + kh;
        f32x16 acc = zero16();
#pragma unroll 4
        for (int i = 0; i < 32; ++i) {
            const float* pa = Ax + i * 16;
            const float* pb = Bw + i * 16;
            float4 a0 = *(const float4*)pa, a1 = *(const float4*)(pa + 4);
            float4 b0 = *(const float4*)pb, b1 = *(const float4*)(pb + 4);
            bf16x8 a, b;
            a[0] = (__bf16)a0.x; a[1] = (__bf16)a0.y; a[2] = (__bf16)a0.z; a[3] = (__bf16)a0.w;
            a[4] = (__bf16)a1.x; a[5] = (__bf16)a1.y; a[6] = (__bf16)a1.z; a[7] = (__bf16)a1.w;
            b[0] = (__bf16)b0.x; b[1] = (__bf16)b0.y; b[2] = (__bf16)b0.z; b[3] = (__bf16)b0.w;
            b[4] = (__bf16)b1.x; b[5] = (__bf16)b1.y; b[6] = (__bf16)b1.z; b[7] = (__bf16)b1.w;
            acc = MFMA(a, b, acc);
        }
#pragma unroll
        for (int r = 0; r < 16; ++r) {
            int row = (r & 3) + 8 * (r >> 2) + 4 * (lane >> 5);
            red[wave * 1024 + row * 32 + l31] = acc[r];
        }
        __syncthreads();
        const int e0 = tid * 4;
        float4 s = {0.f, 0.f, 0.f, 0.f};
#pragma unroll
        for (int w = 0; w < 4; ++w) {
            float4 v = *(const float4*)&red[w * 1024 + e0];
            s.x += v.x; s.y += v.y; s.z += v.z; s.w += v.w;
        }
        const int row = e0 >> 5, col = e0 & 31;
        const int m = mt * 32 + row, n = nt * 32 + col;
        float v[4] = {s.x + in_b[n], s.y + in_b[n + 1], s.z + in_b[n + 2], s.w + in_b[n + 3]};
        *(float4*)(Ebuf + m * SDIM + n) = *(const float4*)v;
        alignas(8) __bf16 o[4];
#pragma unroll
        for (int j = 0; j < 4; ++j) o[j] = (__bf16)fmaxf(v[j], 0.f);
        const size_t frag = (size_t)(m >> 5) * (TOTAL / 16) + (n >> 4);
        const int lh = (m & 31) + 32 * ((n >> 3) & 1);
        *(ushort4*)(H0 + frag * 512 + lh * 8 + (n & 7)) = *(const ushort4*)o;
    } else if (bid < 2304) {
        // ---- W (f32, W[k][n]) -> WT tiled bf16 (r=n, c=k); 16k x 512n tile ----
        const int wb = bid - 256;
        const int k0 = (wb >> 3) * 16;     // 256 k-tiles
        const int n0 = (wb & 7) * 512;     // 8 n-panels
        // stage: 16 rows x 2KB contiguous reads -> t[k][n], float4 LDS writes
#pragma unroll
        for (int i = 0; i < 8; ++i) {
            const int slot = i * 256 + tid;        // 2048 float4 slots
            const int row = slot >> 7;             // 128 float4 per row
            const int c4 = (slot & 127) * 4;
            float4 v = *(const float4*)(W + (size_t)(k0 + row) * TOTAL + n0 + c4);
            *(float4*)&t[row * 512 + c4] = v;
        }
        __syncthreads();
        // emit: 16 frags (rt_local 0..15) at fixed kc; 8x ds_read_b32 column gather
        const int kcG = k0 >> 4;
#pragma unroll
        for (int s = tid; s < 1024; s += 256) {
            const int rtl = s >> 6;
            const int lane = s & 63;
            const int nl = rtl * 32 + (lane & 31);
            const int kl = (lane >> 5) * 8;
            bf16x8 v;
#pragma unroll
            for (int j = 0; j < 8; ++j) v[j] = (__bf16)t[(kl + j) * 512 + nl];
            const size_t fragG = (size_t)((n0 >> 5) + rtl) * (TOTAL / 16) + kcG;
            *(bf16x8*)(WT + fragG * 512 + lane * 8) = v;
        }
    } else {
        swz_slot(out_w, OWT, 1024, NCLS, (bid - 2304) * 256 + tid);
    }
}

// ---- t=1 step (K=1024 only): hn = relu(h @ W) ----
// 256 blocks x 1024 thr (16 waves = 4/SIMD); block tile 64m x 64n; K-split 16.
// (R14-verified.)
template <int CHUNKS>
__global__ __launch_bounds__(1024, 1) void k_step3(const __bf16* __restrict__ h,
                                                   const __bf16* __restrict__ WT,
                                                   const float* __restrict__ E,
                                                   const int gate,
                                                   __bf16* __restrict__ hn) {
    __shared__ float buf[8][4096];   // 128 KiB -> 1 block/CU
    const int w = threadIdx.x >> 6;
    const int lane = threadIdx.x & 63;
    const int xcd = blockIdx.x & 7;
    const int idx = blockIdx.x >> 3;       // 0..31
    const int mt = idx & 3;                // m0 = mt*64
    const int nt = xcd * 8 + (idx >> 2);   // 0..63
    constexpr int PER = CHUNKS >> 4;       // 16-way K-split
    const int kc0 = w * PER;

    const bf16x8* A0 = (const bf16x8*)h  + ((size_t)(mt * 2) * (TOTAL / 16) + kc0) * 64 + lane;
    const bf16x8* A1 = A0 + (size_t)(TOTAL / 16) * 64;
    const bf16x8* B0 = (const bf16x8*)WT + ((size_t)(nt * 2) * (TOTAL / 16) + kc0) * 64 + lane;
    const bf16x8* B1 = B0 + (size_t)(TOTAL / 16) * 64;

    f32x16 ac0 = zero16(), ac1 = zero16(), ac2 = zero16(), ac3 = zero16();
#pragma unroll 4
    for (int i = 0; i < PER; ++i) {
        const int off = i * 64;
        bf16x8 a0 = A0[off];
        bf16x8 a1 = A1[off];
        bf16x8 b0 = B0[off];
        bf16x8 b1 = B1[off];
        ac0 = MFMA(a0, b0, ac0);
        ac1 = MFMA(a0, b1, ac1);
        ac2 = MFMA(a1, b0, ac2);
        ac3 = MFMA(a1, b1, ac3);
    }

    // reduce: idx(c,r,l) = (c*16+r)*64 + l (2-way bank alias: free)
    f32x16 accs[4] = {ac0, ac1, ac2, ac3};
    if (w >= 8) {
        float* b = buf[w - 8];
#pragma unroll
        for (int cc = 0; cc < 4; ++cc)
#pragma unroll
            for (int rr = 0; rr < 16; ++rr)
                b[(cc * 16 + rr) * 64 + lane] = accs[cc][rr];
    }
    __syncthreads();
    if (w < 8) {
        float* b = buf[w];
#pragma unroll
        for (int cc = 0; cc < 4; ++cc)
#pragma unroll
            for (int rr = 0; rr < 16; ++rr) {
                const int i2 = (cc * 16 + rr) * 64 + lane;
                b[i2] += accs[cc][rr];
            }
    }
    __syncthreads();

    // final 8-way sum + epilogue; thread t -> (c, r, 4 lanes from l0)
    const int t = threadIdx.x;
    const int c = t >> 8;            // 0..3
    const int r = (t >> 4) & 15;     // 0..15
    const int l0 = (t & 15) * 4;     // 0..60
    const int base = (c * 16 + r) * 64 + l0;
    float4 s = {0.f, 0.f, 0.f, 0.f};
#pragma unroll
    for (int wb = 0; wb < 8; ++wb) {
        float4 v0 = *(const float4*)&buf[wb][base];
        s.x += v0.x; s.y += v0.y; s.z += v0.z; s.w += v0.w;
    }
    float v[4] = {s.x, s.y, s.z, s.w};
    const int ih = c >> 1, jh = c & 1;
    const int row = ih * 32 + (r & 3) + 8 * (r >> 2) + 4 * (l0 >> 5);
    const int col0 = jh * 32 + (l0 & 31);
    const int m = mt * 64 + row;
    const int n0g = nt * 64 + col0;
    if (gate && n0g < SDIM) {
        const float* Ep = E + m * SDIM + n0g;
#pragma unroll
        for (int j = 0; j < 4; ++j) v[j] += Ep[j];
    }
    alignas(8) __bf16 o[4];
#pragma unroll
    for (int j = 0; j < 4; ++j) o[j] = (__bf16)fmaxf(v[j], 0.f);
    const size_t frag = (size_t)(m >> 5) * (TOTAL / 16) + (n0g >> 4);
    const int lh = (m & 31) + 32 * ((n0g >> 3) & 1);
    *(ushort4*)(hn + frag * 512 + lh * 8 + (n0g & 7)) = *(const ushort4*)o;
}

// ---- full step partial, fat-wave: P[ksg] = h @ W[k-group] (flat loads) ----
// grid 256 x 256 thr (4 waves, 1 wave/SIMD, ~330 VGPR incl 256 acc). Block =
// (mt2, ntp-of-XCD, ksg4): xcd=bid&7, q=bid>>3; ntp=xcd*4+(q&3) (XCD-local WT
// panel), ksg=(q>>2)&3, mt=q>>4. Wave w: FULL 128x128 output tile, K=256
// (k-frags kc0..kc0+15, kc0=(ksg*4+w)*16). 8 loads : 16 MFMA per k16-iter ->
// 128 load-instr/wave, 512/CU (half of R12/R14's 1024). Epilogue: 4-wave LDS
// reduce in 4 row-chunks (barriers only after all loads done), f32 store to P.
__global__ __launch_bounds__(256, 1) void k_partW(const __bf16* __restrict__ h,
                                                  const __bf16* __restrict__ WT,
                                                  float* __restrict__ P) {
    __shared__ float red[4][4096];   // 64 KiB
    const int w = threadIdx.x >> 6;
    const int lane = threadIdx.x & 63;
    const int xcd = blockIdx.x & 7;
    const int q = blockIdx.x >> 3;       // 0..31
    const int ntp = xcd * 4 + (q & 3);   // 0..31 (128-col panel)
    const int ksg = (q >> 2) & 3;        // partial-slice group
    const int mt = q >> 4;               // 0..1  (128-row panel)
    const int kc0 = (ksg * 4 + w) * 16;  // 16 k-frags = 256 k per wave

    const int strideF = (TOTAL / 16) * 64;   // bf16x8 elems per frag-row
    const bf16x8* Ab = (const bf16x8*)h  + ((size_t)(mt * 4) * (TOTAL / 16) + kc0) * 64 + lane;
    const bf16x8* Bb = (const bf16x8*)WT + ((size_t)(ntp * 4) * (TOTAL / 16) + kc0) * 64 + lane;

    f32x16 acc[4][4];
#pragma unroll
    for (int i = 0; i < 4; ++i)
#pragma unroll
        for (int j = 0; j < 4; ++j) acc[i][j] = zero16();

#pragma unroll 2
    for (int i = 0; i < 16; ++i) {
        const int off = i * 64;
        bf16x8 a0 = Ab[off];
        bf16x8 a1 = Ab[off + strideF];
        bf16x8 a2 = Ab[off + 2 * strideF];
        bf16x8 a3 = Ab[off + 3 * strideF];
        bf16x8 b0 = Bb[off];
        bf16x8 b1 = Bb[off + strideF];
        bf16x8 b2 = Bb[off + 2 * strideF];
        bf16x8 b3 = Bb[off + 3 * strideF];
        acc[0][0] = MFMA(a0, b0, acc[0][0]);
        acc[0][1] = MFMA(a0, b1, acc[0][1]);
        acc[0][2] = MFMA(a0, b2, acc[0][2]);
        acc[0][3] = MFMA(a0, b3, acc[0][3]);
        acc[1][0] = MFMA(a1, b0, acc[1][0]);
        acc[1][1] = MFMA(a1, b1, acc[1][1]);
        acc[1][2] = MFMA(a1, b2, acc[1][2]);
        acc[1][3] = MFMA(a1, b3, acc[1][3]);
        acc[2][0] = MFMA(a2, b0, acc[2][0]);
        acc[2][1] = MFMA(a2, b1, acc[2][1]);
        acc[2][2] = MFMA(a2, b2, acc[2][2]);
        acc[2][3] = MFMA(a2, b3, acc[2][3]);
        acc[3][0] = MFMA(a3, b0, acc[3][0]);
        acc[3][1] = MFMA(a3, b1, acc[3][1]);
        acc[3][2] = MFMA(a3, b2, acc[3][2]);
        acc[3][3] = MFMA(a3, b3, acc[3][3]);
    }

    // epilogue: 4 chunks (acc row-block c = 32 rows x 128 cols); per chunk:
    // each wave writes 16KB to red[w] ([32][128] f32), sync, 256 threads sum
    // 4 bufs + coalesced f32x4 store to P, sync. Fully unrolled (static acc idx).
    const int m0 = mt * 128;
    const int n0 = ntp * 128;
    float* Pg = P + (size_t)ksg * (BATCH * TOTAL);
    const int l31 = lane & 31;
    const int rb = 4 * (lane >> 5);
#pragma unroll
    for (int c = 0; c < 4; ++c) {
        float* b = red[w];
#pragma unroll
        for (int j = 0; j < 4; ++j)
#pragma unroll
            for (int r = 0; r < 16; ++r) {
                const int rl = (r & 3) + 8 * (r >> 2) + rb;
                b[rl * 128 + j * 32 + l31] = acc[c][j][r];
            }
        __syncthreads();
#pragma unroll
        for (int p = 0; p < 4; ++p) {
            const int e = p * 1024 + threadIdx.x * 4;
            float4 s0 = *(const float4*)&red[0][e];
            float4 s1 = *(const float4*)&red[1][e];
            float4 s2 = *(const float4*)&red[2][e];
            float4 s3 = *(const float4*)&red[3][e];
            float4 s = {s0.x + s1.x + s2.x + s3.x, s0.y + s1.y + s2.y + s3.y,
                        s0.z + s1.z + s2.z + s3.z, s0.w + s1.w + s2.w + s3.w};
            const int rl = e >> 7, cl = e & 127;
            *(float4*)(Pg + (size_t)(m0 + c * 32 + rl) * TOTAL + n0 + cl) = s;
        }
        if (c < 3) __syncthreads();
    }
}

// ---- per-step reduce: hn = relu(sum_{ks<4} P[ks] + gate*[E,0,0]) -> tiled bf16 ----
// (R13/R15-verified against this P layout.)
__global__ __launch_bounds__(256) void k_red2(const float* __restrict__ P,
                                              const float* __restrict__ E,
                                              const int gate,
                                              __bf16* __restrict__ hn) {
    const int g = blockIdx.x * 256 + threadIdx.x;   // 0..131071
    const int m = g >> 9;
    const int n8 = (g & 511) << 3;
    const float* p = P + (size_t)m * TOTAL + n8;
    float4 a0 = *(const float4*)p, a1 = *(const float4*)(p + 4);
#pragma unroll
    for (int s = 1; s < 4; ++s) {
        const float* q = p + (size_t)s * (BATCH * TOTAL);
        float4 b0 = *(const float4*)q, b1 = *(const float4*)(q + 4);
        a0.x += b0.x; a0.y += b0.y; a0.z += b0.z; a0.w += b0.w;
        a1.x += b1.x; a1.y += b1.y; a1.z += b1.z; a1.w += b1.w;
    }
    if (gate && n8 < SDIM) {
        const float* Ep = E + (size_t)m * SDIM + n8;
        float4 e0 = *(const float4*)Ep, e1 = *(const float4*)(Ep + 4);
        a0.x += e0.x; a0.y += e0.y; a0.z += e0.z; a0.w += e0.w;
        a1.x += e1.x; a1.y += e1.y; a1.z += e1.z; a1.w += e1.w;
    }
    alignas(16) __bf16 o[8];
    o[0] = (__bf16)fmaxf(a0.x, 0.f); o[1] = (__bf16)fmaxf(a0.y, 0.f);
    o[2] = (__bf16)fmaxf(a0.z, 0.f); o[3] = (__bf16)fmaxf(a0.w, 0.f);
    o[4] = (__bf16)fmaxf(a1.x, 0.f); o[5] = (__bf16)fmaxf(a1.y, 0.f);
    o[6] = (__bf16)fmaxf(a1.z, 0.f); o[7] = (__bf16)fmaxf(a1.w, 0.f);
    const size_t frag = (size_t)(m >> 5) * (TOTAL / 16) + (n8 >> 4);
    const int lh = (m & 31) + 32 * ((n8 >> 3) & 1);
    *(ulonglong2*)(hn + frag * 512 + lh * 8) = *(const ulonglong2*)o;
}

// ---- t=9 partial: P[ks] = h9 @ W[kslice, 3072:4096] (no relu, no gate) ----
__global__ __launch_bounds__(512, 2) void k_part9(const __bf16* __restrict__ h,
                                                  const __bf16* __restrict__ WT,
                                                  float* __restrict__ P) {
    __shared__ float buf[4][4096];
    const int wave = threadIdx.x >> 6;
    const int lane = threadIdx.x & 63;
    const int xcd = blockIdx.x & 7;
    const int idx = blockIdx.x >> 3;             // 0..31
    const int nt = 48 + xcd * 2 + (idx >> 4);    // 48..63 (O panel)
    const int mt = (idx >> 2) & 3;
    const int ks = idx & 3;
    const int kc0 = ks * 64 + wave * 8;          // 8 chunks/wave = 128 k

    const bf16x8* A0 = (const bf16x8*)h  + ((size_t)(mt * 2) * (TOTAL / 16) + kc0) * 64 + lane;
    const bf16x8* A1 = A0 + (size_t)(TOTAL / 16) * 64;
    const bf16x8* B0 = (const bf16x8*)WT + ((size_t)(nt * 2) * (TOTAL / 16) + kc0) * 64 + lane;
    const bf16x8* B1 = B0 + (size_t)(TOTAL / 16) * 64;

    f32x16 ac0 = zero16(), ac1 = zero16(), ac2 = zero16(), ac3 = zero16();
#pragma unroll 4
    for (int i = 0; i < 8; ++i) {
        const int off = i * 64;
        bf16x8 a0 = A0[off];
        bf16x8 a1 = A1[off];
        bf16x8 b0 = B0[off];
        bf16x8 b1 = B1[off];
        ac0 = MFMA(a0, b0, ac0);
        ac1 = MFMA(a0, b1, ac1);
        ac2 = MFMA(a1, b0, ac2);
        ac3 = MFMA(a1, b1, ac3);
    }

    f32x16 accs[4] = {ac0, ac1, ac2, ac3};
    if (wave >= 4) {
        float* b = buf[wave - 4];
#pragma unroll
        for (int c = 0; c < 4; ++c)
#pragma unroll
            for (int r = 0; r < 16; ++r)
                b[(c * 16 + r) * 64 + lane] = accs[c][r];
    }
    __syncthreads();
    if (wave < 4) {
        float* b = buf[wave];
#pragma unroll
        for (int c = 0; c < 4; ++c)
#pragma unroll
            for (int r = 0; r < 16; ++r) {
                const int i2 = (c * 16 + r) * 64 + lane;
                b[i2] += accs[c][r];
            }
    }
    __syncthreads();

    const int t = threadIdx.x;
    const int c = t >> 7;
    const int r = (t >> 3) & 15;
    const int l0 = (t & 7) * 8;
    const int base = (c * 16 + r) * 64 + l0;
    float4 s0 = {0.f, 0.f, 0.f, 0.f}, s1 = {0.f, 0.f, 0.f, 0.f};
#pragma unroll
    for (int w = 0; w < 4; ++w) {
        const float4* p = (const float4*)&buf[w][base];
        float4 v0 = p[0], v1 = p[1];
        s0.x += v0.x; s0.y += v0.y; s0.z += v0.z; s0.w += v0.w;
        s1.x += v1.x; s1.y += v1.y; s1.z += v1.z; s1.w += v1.w;
    }
    alignas(16) float v[8] = {s0.x, s0.y, s0.z, s0.w, s1.x, s1.y, s1.z, s1.w};
    const int ih = c >> 1, jh = c & 1;
    const int row = ih * 32 + (r & 3) + 8 * (r >> 2) + 4 * (l0 >> 5);
    const int col0 = jh * 32 + (l0 & 31);
    const int m = mt * 64 + row;
    const int nl = (nt - 48) * 64 + col0;        // 0..1023 (O-local)
    float* p = P + ((size_t)ks << 18) + (size_t)m * 1024 + nl;
    *(float4*)p = *(const float4*)&v[0];
    *(float4*)(p + 4) = *(const float4*)&v[4];
}

// ---- t=9 reduce: h10_O = relu(sum_ks P[ks]) -> bf16 swizzled frags ----
__global__ __launch_bounds__(256) void k_red9(const float* __restrict__ P,
                                              __bf16* __restrict__ hn) {
    const int g = blockIdx.x * 256 + threadIdx.x;   // 0..32767
    const int m = g >> 7;
    const int n8 = (g & 127) << 3;
    const float* p = P + (size_t)m * 1024 + n8;
    float4 a0 = *(const float4*)p, a1 = *(const float4*)(p + 4);
#pragma unroll
    for (int ks = 1; ks < 4; ++ks) {
        const float* q = p + ((size_t)ks << 18);
        float4 b0 = *(const float4*)q, b1 = *(const float4*)(q + 4);
        a0.x += b0.x; a0.y += b0.y; a0.z += b0.z; a0.w += b0.w;
        a1.x += b1.x; a1.y += b1.y; a1.z += b1.z; a1.w += b1.w;
    }
    alignas(16) __bf16 o[8];
    o[0] = (__bf16)fmaxf(a0.x, 0.f); o[1] = (__bf16)fmaxf(a0.y, 0.f);
    o[2] = (__bf16)fmaxf(a0.z, 0.f); o[3] = (__bf16)fmaxf(a0.w, 0.f);
    o[4] = (__bf16)fmaxf(a1.x, 0.f); o[5] = (__bf16)fmaxf(a1.y, 0.f);
    o[6] = (__bf16)fmaxf(a1.z, 0.f); o[7] = (__bf16)fmaxf(a1.w, 0.f);
    const int n0g = 3072 + n8;
    const size_t frag = (size_t)(m >> 5) * (TOTAL / 16) + (n0g >> 4);
    const int lh = (m & 31) + 32 * ((n0g >> 3) & 1);
    *(ulonglong2*)(hn + frag * 512 + lh * 8) = *(const ulonglong2*)o;
}

// ---- out = h[:, 3072:] @ out_w^T + out_b (h tiled, out_w tiled padded to 1024 rows) ----
__global__ __launch_bounds__(512, 4) void k_out(const __bf16* __restrict__ h,
                                                const __bf16* __restrict__ owt,
                                                const float* __restrict__ out_b,
                                                float* __restrict__ out) {
    __shared__ float red[8][1024];
    const int wave = threadIdx.x >> 6;
    const int lane = threadIdx.x & 63;
    const int mt = blockIdx.x >> 5;
    const int ct = blockIdx.x & 31;
    const int m0 = mt * 32, c0 = ct * 32;
    const int kcA0 = (3072 / 16) + wave * 8;
    const int kcB0 = wave * 8;
    const bf16x8* Ap = (const bf16x8*)h   + ((size_t)mt * (TOTAL / 16) + kcA0) * 64 + lane;
    const bf16x8* Bp = (const bf16x8*)owt + ((size_t)ct * (1024 / 16) + kcB0) * 64 + lane;
    f32x16 acc = zero16();
#pragma unroll
    for (int i = 0; i < 8; ++i)
        acc = MFMA(Ap[i * 64], Bp[i * 64], acc);
#pragma unroll
    for (int r = 0; r < 16; ++r) {
        int row = (r & 3) + 8 * (r >> 2) + 4 * (lane >> 5);
        red[wave][row * 32 + (lane & 31)] = acc[r];
    }
    __syncthreads();
    const int e0 = threadIdx.x * 2;
    float sx = 0.f, sy = 0.f;
#pragma unroll
    for (int w = 0; w < 8; ++w) {
        float2 v = *(const float2*)&red[w][e0];
        sx += v.x; sy += v.y;
    }
    const int row = e0 >> 5, col = e0 & 31;
    const int m = m0 + row;
    const int n = c0 + col;
    if (n < NCLS)     out[m * NCLS + n]     = sx + out_b[n];
    if (n + 1 < NCLS) out[m * NCLS + n + 1] = sy + out_b[n + 1];
}

extern "C" void kernel_launch(void* const* d_in, const int* in_sizes, int n_in,
                              void* d_out, int out_size, void* d_ws, size_t ws_size,
                              hipStream_t stream) {
    const float* x     = (const float*)d_in[0];   // 256 x 2048
    const float* W     = (const float*)d_in[1];   // 4096 x 4096
    const float* in_w  = (const float*)d_in[2];   // 1024 x 2048
    const float* in_b  = (const float*)d_in[3];   // 1024
    const float* out_w = (const float*)d_in[4];   // 1000 x 1024
    const float* out_b = (const float*)d_in[5];   // 1000
    float* out = (float*)d_out;                   // 256 x 1000

    char* ws = (char*)d_ws;
    __bf16* WT  = (__bf16*)(ws + 0);          // 32 MiB  W^T tiled (r=n, c=k)
    __bf16* OWT = (__bf16*)(ws + 33554432);   // 2 MiB   out_w tiled (padded 1024 rows)
    float*  Ebuf= (float*)(ws + 35651584);    // 1 MiB   E f32 row-major
    __bf16* H0  = (__bf16*)(ws + 36700160);   // 2 MiB   h tiled
    __bf16* H1  = (__bf16*)(ws + 38797312);   // 2 MiB   h tiled
    float*  Pbuf= (float*)(ws + 40894464);    // 16 MiB  f32 partials (4 x 256 x 4096)

    // prep: E-GEMM (writes Ebuf + H0 relu'd) + W transpose-swizzle + out_w swizzle.
    // t=0 collapses to h1 = [relu(E),0,0]; step t=1 reads only K<1024 so H0's upper
    // region needs no memset.
    k_prep<<<2816, 256, 0, stream>>>(W, x, in_w, in_b, out_w, WT, OWT, Ebuf, H0);

    const __bf16* hs = H0;
    __bf16* hd = H1;

    // t=1: K=1024 only (h1 = [relu(E),0,0]); gate=0
    k_step3<SDIM / 16><<<256, 1024, 0, stream>>>(hs, WT, Ebuf, 0, hd);
    { const __bf16* tmp = hs; hs = hd; hd = (__bf16*)tmp; }

    // t=2..8 full steps: fat-wave 128x128 k-split-4 partials + reduce (gate at t=5)
    for (int t = 2; t < 9; ++t) {
        k_partW<<<256, 256, 0, stream>>>(hs, WT, Pbuf);
        k_red2<<<512, 256, 0, stream>>>(Pbuf, Ebuf, (t % 5 == 0) ? 1 : 0, hd);
        const __bf16* tmp = hs; hs = hd; hd = (__bf16*)tmp;
    }

    // t=9: only the O-panel feeds k_out -> 1/4 work, k-split x4 + reduce
    k_part9<<<256, 512, 0, stream>>>(hs, WT, Pbuf);
    k_red9<<<128, 256, 0, stream>>>(Pbuf, hd);

    k_out<<<256, 512, 0, stream>>>(hd, OWT, out_b, out);
}

// Round 9
// 324.736 us; speedup vs baseline: 1.0706x; 1.0706x over previous
//
#include <hip/hip_runtime.h>

// BasicRNN R19 = R18 resubmit (container failed twice = infra flake; kernel audited
// for hang hazards: uniform barriers, per-wave vmcnt retires exactly stage(c),
// buffer overwrite protected by barrier #1 — no deadlock path found).
// Full steps = R16's verified k_stepL with ONLY the sync pattern changed to T4
// (counted vmcnt + raw s_barrier). Model fitting R12-R17:
// step time = max(consumed bytes/CU / ~19 B/cyc, latency exposure). R12/R14 sit ON
// the byte floor (1.1MB->26us). R16 staged only 0.77MB/CU but ran ~30us because
// {stage(c+1); compute(c); __syncthreads} drains vmcnt(0) INCLUDING the c+1
// prefetch -> every chunk serialized behind next chunk's loads (guide §5 stall;
// m218: counted-vs-drain0 +38-73%). Loop per chunk:
//   s_barrier (buf free) -> stage(c+1) -> s_waitcnt vmcnt(4) (c landed, c+1 flies)
//   -> s_barrier -> compute(c);  sched_barrier(0) pins after barriers.
// Predicted: stepP ~15.5us + red8 ~5.5 = 21us/step vs 26 -> total ~222us.
// FALSIFIER: total >= ~258 -> gload_lds intrinsic penalty -> revert to R14 for
// good. Second container failure -> kernel implicated -> drop raw-asm schedule.
// t=1 (k_step3<64>), t=9 (part9/red9), prep, out unchanged from R14 (257.6us).
// Fragment-tiled operands:
//   elem(r,c) = frag*512 + lane*8 + (c&7), frag=(r>>5)*(C/16)+(c>>4), lane=(r&31)+32*((c>>3)&1)

typedef __bf16 bf16x8 __attribute__((ext_vector_type(8)));
typedef float  f32x16 __attribute__((ext_vector_type(16)));

#define TOTAL 4096
#define BATCH 256
#define INDIM 2048
#define SDIM  1024
#define NCLS  1000

#define MFMA(a, b, c) __builtin_amdgcn_mfma_f32_32x32x16_bf16((a), (b), (c), 0, 0, 0)

__device__ inline f32x16 zero16() {
    f32x16 v;
#pragma unroll
    for (int i = 0; i < 16; ++i) v[i] = 0.f;
    return v;
}

// async global->LDS, 16B per lane; LDS dest wave-uniform base + lane*16 (R13/R16-verified)
__device__ inline void gload_lds16(const void* g, void* l) {
    __builtin_amdgcn_global_load_lds(
        (__attribute__((address_space(1))) void*)(const_cast<void*>(g)),
        (__attribute__((address_space(3))) void*)l,
        16, 0, 0);
}

__device__ inline void swz_slot(const float* __restrict__ in, __bf16* __restrict__ out,
                                int C, int Rvalid, int t) {
    const int lane = t & 63;
    const int frag = t >> 6;
    const int kcN = C >> 4;
    const int rt = frag / kcN;
    const int kc = frag - rt * kcN;
    const int r = rt * 32 + (lane & 31);
    const int c = kc * 16 + (lane >> 5) * 8;
    alignas(16) __bf16 v[8];
    if (r < Rvalid) {
        const float* p = in + (size_t)r * C + c;
#pragma unroll
        for (int j = 0; j < 8; ++j) v[j] = (__bf16)p[j];
    } else {
#pragma unroll
        for (int j = 0; j < 8; ++j) v[j] = (__bf16)0.f;
    }
    *(ulonglong2*)(out + (size_t)t * 8) = *(const ulonglong2*)v;
}

// ---- merged preprocessing + E-GEMM ----
// grid 2816 x 256: [0,256) E-GEMM; [256,2304) W transpose-swizzle (16k x 512n tiles);
//                  [2304,2816) out_w swizzle
__global__ __launch_bounds__(256) void k_prep(const float* __restrict__ W,
                                              const float* __restrict__ x,
                                              const float* __restrict__ in_w,
                                              const float* __restrict__ in_b,
                                              const float* __restrict__ out_w,
                                              __bf16* __restrict__ WT,
                                              __bf16* __restrict__ OWT,
                                              float* __restrict__ Ebuf,
                                              __bf16* __restrict__ H0) {
    __shared__ float t[16 * 512];   // 32 KB; E path reuses first 4x1024 as reduce buf
    const int bid = blockIdx.x;
    const int tid = threadIdx.x;
    if (bid < 256) {
        // ---- E = x @ in_w^T + in_b ; H0[:, :1024] = relu(E) (tiled) ----
        float* red = t;   // 4 x 1024
        const int mt = bid >> 5, nt = bid & 31;
        const int wave = tid >> 6, lane = tid & 63;
        const int l31 = lane & 31, kh = (lane >> 5) * 8;
        const int k0 = wave * 512;
        const float* Ax = x    + (size_t)(mt * 32 + l31) * INDIM + k0 + kh;
        const float* Bw = in_w + (size_t)(nt * 32 + l31) * INDIM + k0 + kh;
        f32x16 acc = zero16();
#pragma unroll 4
        for (int i = 0; i < 32; ++i) {
            const float* pa = Ax + i * 16;
            const float* pb = Bw + i * 16;
            float4 a0 = *(const float4*)pa, a1 = *(const float4*)(pa + 4);
            float4 b0 = *(const float4*)pb, b1 = *(const float4*)(pb + 4);
            bf16x8 a, b;
            a[0] = (__bf16)a0.x; a[1] = (__bf16)a0.y; a[2] = (__bf16)a0.z; a[3] = (__bf16)a0.w;
            a[4] = (__bf16)a1.x; a[5] = (__bf16)a1.y; a[6] = (__bf16)a1.z; a[7] = (__bf16)a1.w;
            b[0] = (__bf16)b0.x; b[1] = (__bf16)b0.y; b[2] = (__bf16)b0.z; b[3] = (__bf16)b0.w;
            b[4] = (__bf16)b1.x; b[5] = (__bf16)b1.y; b[6] = (__bf16)b1.z; b[7] = (__bf16)b1.w;
            acc = MFMA(a, b, acc);
        }
#pragma unroll
        for (int r = 0; r < 16; ++r) {
            int row = (r & 3) + 8 * (r >> 2) + 4 * (lane >> 5);
            red[wave * 1024 + row * 32 + l31] = acc[r];
        }
        __syncthreads();
        const int e0 = tid * 4;
        float4 s = {0.f, 0.f, 0.f, 0.f};
#pragma unroll
        for (int w = 0; w < 4; ++w) {
            float4 v = *(const float4*)&red[w * 1024 + e0];
            s.x += v.x; s.y += v.y; s.z += v.z; s.w += v.w;
        }
        const int row = e0 >> 5, col = e0 & 31;
        const int m = mt * 32 + row, n = nt * 32 + col;
        float v[4] = {s.x + in_b[n], s.y + in_b[n + 1], s.z + in_b[n + 2], s.w + in_b[n + 3]};
        *(float4*)(Ebuf + m * SDIM + n) = *(const float4*)v;
        alignas(8) __bf16 o[4];
#pragma unroll
        for (int j = 0; j < 4; ++j) o[j] = (__bf16)fmaxf(v[j], 0.f);
        const size_t frag = (size_t)(m >> 5) * (TOTAL / 16) + (n >> 4);
        const int lh = (m & 31) + 32 * ((n >> 3) & 1);
        *(ushort4*)(H0 + frag * 512 + lh * 8 + (n & 7)) = *(const ushort4*)o;
    } else if (bid < 2304) {
        // ---- W (f32, W[k][n]) -> WT tiled bf16 (r=n, c=k); 16k x 512n tile ----
        const int wb = bid - 256;
        const int k0 = (wb >> 3) * 16;     // 256 k-tiles
        const int n0 = (wb & 7) * 512;     // 8 n-panels
        // stage: 16 rows x 2KB contiguous reads -> t[k][n], float4 LDS writes
#pragma unroll
        for (int i = 0; i < 8; ++i) {
            const int slot = i * 256 + tid;        // 2048 float4 slots
            const int row = slot >> 7;             // 128 float4 per row
            const int c4 = (slot & 127) * 4;
            float4 v = *(const float4*)(W + (size_t)(k0 + row) * TOTAL + n0 + c4);
            *(float4*)&t[row * 512 + c4] = v;
        }
        __syncthreads();
        // emit: 16 frags (rt_local 0..15) at fixed kc; 8x ds_read_b32 column gather
        const int kcG = k0 >> 4;
#pragma unroll
        for (int s = tid; s < 1024; s += 256) {
            const int rtl = s >> 6;
            const int lane = s & 63;
            const int nl = rtl * 32 + (lane & 31);
            const int kl = (lane >> 5) * 8;
            bf16x8 v;
#pragma unroll
            for (int j = 0; j < 8; ++j) v[j] = (__bf16)t[(kl + j) * 512 + nl];
            const size_t fragG = (size_t)((n0 >> 5) + rtl) * (TOTAL / 16) + kcG;
            *(bf16x8*)(WT + fragG * 512 + lane * 8) = v;
        }
    } else {
        swz_slot(out_w, OWT, 1024, NCLS, (bid - 2304) * 256 + tid);
    }
}

// ---- t=1 step (K=1024 only): hn = relu(h @ W) ----
// 256 blocks x 1024 thr (16 waves = 4/SIMD); block tile 64m x 64n; K-split 16.
// (R14-verified.)
template <int CHUNKS>
__global__ __launch_bounds__(1024, 1) void k_step3(const __bf16* __restrict__ h,
                                                   const __bf16* __restrict__ WT,
                                                   const float* __restrict__ E,
                                                   const int gate,
                                                   __bf16* __restrict__ hn) {
    __shared__ float buf[8][4096];   // 128 KiB -> 1 block/CU
    const int w = threadIdx.x >> 6;
    const int lane = threadIdx.x & 63;
    const int xcd = blockIdx.x & 7;
    const int idx = blockIdx.x >> 3;       // 0..31
    const int mt = idx & 3;                // m0 = mt*64
    const int nt = xcd * 8 + (idx >> 2);   // 0..63
    constexpr int PER = CHUNKS >> 4;       // 16-way K-split
    const int kc0 = w * PER;

    const bf16x8* A0 = (const bf16x8*)h  + ((size_t)(mt * 2) * (TOTAL / 16) + kc0) * 64 + lane;
    const bf16x8* A1 = A0 + (size_t)(TOTAL / 16) * 64;
    const bf16x8* B0 = (const bf16x8*)WT + ((size_t)(nt * 2) * (TOTAL / 16) + kc0) * 64 + lane;
    const bf16x8* B1 = B0 + (size_t)(TOTAL / 16) * 64;

    f32x16 ac0 = zero16(), ac1 = zero16(), ac2 = zero16(), ac3 = zero16();
#pragma unroll 4
    for (int i = 0; i < PER; ++i) {
        const int off = i * 64;
        bf16x8 a0 = A0[off];
        bf16x8 a1 = A1[off];
        bf16x8 b0 = B0[off];
        bf16x8 b1 = B1[off];
        ac0 = MFMA(a0, b0, ac0);
        ac1 = MFMA(a0, b1, ac1);
        ac2 = MFMA(a1, b0, ac2);
        ac3 = MFMA(a1, b1, ac3);
    }

    // reduce: idx(c,r,l) = (c*16+r)*64 + l (2-way bank alias: free)
    f32x16 accs[4] = {ac0, ac1, ac2, ac3};
    if (w >= 8) {
        float* b = buf[w - 8];
#pragma unroll
        for (int cc = 0; cc < 4; ++cc)
#pragma unroll
            for (int rr = 0; rr < 16; ++rr)
                b[(cc * 16 + rr) * 64 + lane] = accs[cc][rr];
    }
    __syncthreads();
    if (w < 8) {
        float* b = buf[w];
#pragma unroll
        for (int cc = 0; cc < 4; ++cc)
#pragma unroll
            for (int rr = 0; rr < 16; ++rr) {
                const int i2 = (cc * 16 + rr) * 64 + lane;
                b[i2] += accs[cc][rr];
            }
    }
    __syncthreads();

    // final 8-way sum + epilogue; thread t -> (c, r, 4 lanes from l0)
    const int t = threadIdx.x;
    const int c = t >> 8;            // 0..3
    const int r = (t >> 4) & 15;     // 0..15
    const int l0 = (t & 15) * 4;     // 0..60
    const int base = (c * 16 + r) * 64 + l0;
    float4 s = {0.f, 0.f, 0.f, 0.f};
#pragma unroll
    for (int wb = 0; wb < 8; ++wb) {
        float4 v0 = *(const float4*)&buf[wb][base];
        s.x += v0.x; s.y += v0.y; s.z += v0.z; s.w += v0.w;
    }
    float v[4] = {s.x, s.y, s.z, s.w};
    const int ih = c >> 1, jh = c & 1;
    const int row = ih * 32 + (r & 3) + 8 * (r >> 2) + 4 * (l0 >> 5);
    const int col0 = jh * 32 + (l0 & 31);
    const int m = mt * 64 + row;
    const int n0g = nt * 64 + col0;
    if (gate && n0g < SDIM) {
        const float* Ep = E + m * SDIM + n0g;
#pragma unroll
        for (int j = 0; j < 4; ++j) v[j] += Ep[j];
    }
    alignas(8) __bf16 o[4];
#pragma unroll
    for (int j = 0; j < 4; ++j) o[j] = (__bf16)fmaxf(v[j], 0.f);
    const size_t frag = (size_t)(m >> 5) * (TOTAL / 16) + (n0g >> 4);
    const int lh = (m & 31) + 32 * ((n0g >> 3) & 1);
    *(ushort4*)(hn + frag * 512 + lh * 8 + (n0g & 7)) = *(const ushort4*)o;
}

// ---- full step partial, LDS-staged + T4 counted vmcnt: P[ks] = h @ W[kslice] ----
// grid 512 x 512 thr (8 waves, 64KB LDS -> 2 blocks/CU). Block = (mt2, nt32, ks8):
// xcd = bid&7, nt = xcd*4 + (q&3), ks=(q>>2)&7, mt=q>>5. Wave w: (wm=w>>2, wn=w&3)
// -> 64m x 32n output. K=512/block = 8 chunks of BK=64 (32 frags), dbuf 2x32KB.
// Per chunk: s_barrier (buf free) -> stage(c+1) (4 gload_lds/wave) -> vmcnt(4)
// (stage(c) landed; c+1 still in flight) -> s_barrier -> compute(c).
// Identical math/indexing/stores to R16's verified k_stepL.
__global__ __launch_bounds__(512, 4) void k_stepP(const __bf16* __restrict__ h,
                                                  const __bf16* __restrict__ WT,
                                                  float* __restrict__ P) {
    __shared__ __bf16 sm[2][32 * 512];   // 2 x 32 KB
    const int w = threadIdx.x >> 6;
    const int lane = threadIdx.x & 63;
    const int xcd = blockIdx.x & 7;
    const int q = blockIdx.x >> 3;        // 0..63
    const int nt = xcd * 4 + (q & 3);     // 0..31 (128-col panel)
    const int ks = (q >> 2) & 7;          // 0..7
    const int mt = q >> 5;                // 0..1 (128-row panel)
    const int wm = w >> 2, wn = w & 3;    // wave: 64m x 32n
    const int kb = ks * 32;               // k16-frag base (32 frags = 512 k)

    // frag slot fl (0..31): A: fl = fr*4 + kf (fr 0..3); B: fl-16 = fn*4 + kf
    auto stage = [&](int b, int c) {
        const int kc = kb + c * 4;
#pragma unroll
        for (int i = 0; i < 4; ++i) {
            const int fl = w * 4 + i;
            const int kf = fl & 3;
            const void* src;
            if (fl < 16) {
                src = (const void*)(h + ((size_t)((mt * 4 + (fl >> 2)) * (TOTAL / 16) + kc + kf)) * 512 + lane * 8);
            } else {
                src = (const void*)(WT + ((size_t)((nt * 4 + ((fl - 16) >> 2)) * (TOTAL / 16) + kc + kf)) * 512 + lane * 8);
            }
            gload_lds16(src, (void*)&sm[b][fl * 512]);
        }
    };

    f32x16 ac0 = zero16(), ac1 = zero16();
    stage(0, 0);
    for (int c = 0; c < 8; ++c) {
        __builtin_amdgcn_s_barrier();                 // buf[(c+1)&1] free for overwrite
        __builtin_amdgcn_sched_barrier(0);
        if (c < 7) {
            stage((c + 1) & 1, c + 1);                // issue next chunk (stays in flight)
            asm volatile("s_waitcnt vmcnt(4)" ::: "memory");   // stage(c) landed
        } else {
            asm volatile("s_waitcnt vmcnt(0)" ::: "memory");
        }
        __builtin_amdgcn_s_barrier();                 // ALL waves' stage(c) in LDS
        __builtin_amdgcn_sched_barrier(0);
        const __bf16* As = &sm[c & 1][(wm * 8) * 512];        // frs wm*2, wm*2+1
        const __bf16* Bs = &sm[c & 1][(16 + wn * 4) * 512];   // fn = wn
#pragma unroll
        for (int kf = 0; kf < 4; ++kf) {
            bf16x8 b  = *(const bf16x8*)(Bs + kf * 512 + lane * 8);
            bf16x8 a0 = *(const bf16x8*)(As + kf * 512 + lane * 8);
            bf16x8 a1 = *(const bf16x8*)(As + (4 + kf) * 512 + lane * 8);
            ac0 = MFMA(a0, b, ac0);
            ac1 = MFMA(a1, b, ac1);
        }
    }

    // write 64x32 f32 partial (C/D: col=lane&31, row=(r&3)+8*(r>>2)+4*(lane>>5))
    const int m0 = mt * 128 + wm * 64;
    const int n0 = nt * 128 + wn * 32 + (lane & 31);
    const int rb = 4 * (lane >> 5);
    float* Pp = P + (size_t)ks * (BATCH * TOTAL) + (size_t)m0 * TOTAL + n0;
#pragma unroll
    for (int r = 0; r < 16; ++r) {
        const int row = (r & 3) + 8 * (r >> 2) + rb;
        Pp[(size_t)row * TOTAL] = ac0[r];
        Pp[(size_t)(row + 32) * TOTAL] = ac1[r];
    }
}

// ---- per-step reduce: hn = relu(sum_{ks<8} P[ks] + gate*[E,0,0]) -> tiled bf16 ----
// (R16-verified against this P layout.)
__global__ __launch_bounds__(256) void k_red8(const float* __restrict__ P,
                                              const float* __restrict__ E,
                                              const int gate,
                                              __bf16* __restrict__ hn) {
    const int g = blockIdx.x * 256 + threadIdx.x;   // 0..131071
    const int m = g >> 9;
    const int n8 = (g & 511) << 3;
    const float* p = P + (size_t)m * TOTAL + n8;
    float4 a0 = *(const float4*)p, a1 = *(const float4*)(p + 4);
#pragma unroll
    for (int s = 1; s < 8; ++s) {
        const float* q = p + (size_t)s * (BATCH * TOTAL);
        float4 b0 = *(const float4*)q, b1 = *(const float4*)(q + 4);
        a0.x += b0.x; a0.y += b0.y; a0.z += b0.z; a0.w += b0.w;
        a1.x += b1.x; a1.y += b1.y; a1.z += b1.z; a1.w += b1.w;
    }
    if (gate && n8 < SDIM) {
        const float* Ep = E + (size_t)m * SDIM + n8;
        float4 e0 = *(const float4*)Ep, e1 = *(const float4*)(Ep + 4);
        a0.x += e0.x; a0.y += e0.y; a0.z += e0.z; a0.w += e0.w;
        a1.x += e1.x; a1.y += e1.y; a1.z += e1.z; a1.w += e1.w;
    }
    alignas(16) __bf16 o[8];
    o[0] = (__bf16)fmaxf(a0.x, 0.f); o[1] = (__bf16)fmaxf(a0.y, 0.f);
    o[2] = (__bf16)fmaxf(a0.z, 0.f); o[3] = (__bf16)fmaxf(a0.w, 0.f);
    o[4] = (__bf16)fmaxf(a1.x, 0.f); o[5] = (__bf16)fmaxf(a1.y, 0.f);
    o[6] = (__bf16)fmaxf(a1.z, 0.f); o[7] = (__bf16)fmaxf(a1.w, 0.f);
    const size_t frag = (size_t)(m >> 5) * (TOTAL / 16) + (n8 >> 4);
    const int lh = (m & 31) + 32 * ((n8 >> 3) & 1);
    *(ulonglong2*)(hn + frag * 512 + lh * 8) = *(const ulonglong2*)o;
}

// ---- t=9 partial: P[ks] = h9 @ W[kslice, 3072:4096] (no relu, no gate) ----
__global__ __launch_bounds__(512, 2) void k_part9(const __bf16* __restrict__ h,
                                                  const __bf16* __restrict__ WT,
                                                  float* __restrict__ P) {
    __shared__ float buf[4][4096];
    const int wave = threadIdx.x >> 6;
    const int lane = threadIdx.x & 63;
    const int xcd = blockIdx.x & 7;
    const int idx = blockIdx.x >> 3;             // 0..31
    const int nt = 48 + xcd * 2 + (idx >> 4);    // 48..63 (O panel)
    const int mt = (idx >> 2) & 3;
    const int ks = idx & 3;
    const int kc0 = ks * 64 + wave * 8;          // 8 chunks/wave = 128 k

    const bf16x8* A0 = (const bf16x8*)h  + ((size_t)(mt * 2) * (TOTAL / 16) + kc0) * 64 + lane;
    const bf16x8* A1 = A0 + (size_t)(TOTAL / 16) * 64;
    const bf16x8* B0 = (const bf16x8*)WT + ((size_t)(nt * 2) * (TOTAL / 16) + kc0) * 64 + lane;
    const bf16x8* B1 = B0 + (size_t)(TOTAL / 16) * 64;

    f32x16 ac0 = zero16(), ac1 = zero16(), ac2 = zero16(), ac3 = zero16();
#pragma unroll 4
    for (int i = 0; i < 8; ++i) {
        const int off = i * 64;
        bf16x8 a0 = A0[off];
        bf16x8 a1 = A1[off];
        bf16x8 b0 = B0[off];
        bf16x8 b1 = B1[off];
        ac0 = MFMA(a0, b0, ac0);
        ac1 = MFMA(a0, b1, ac1);
        ac2 = MFMA(a1, b0, ac2);
        ac3 = MFMA(a1, b1, ac3);
    }

    f32x16 accs[4] = {ac0, ac1, ac2, ac3};
    if (wave >= 4) {
        float* b = buf[wave - 4];
#pragma unroll
        for (int c = 0; c < 4; ++c)
#pragma unroll
            for (int r = 0; r < 16; ++r)
                b[(c * 16 + r) * 64 + lane] = accs[c][r];
    }
    __syncthreads();
    if (wave < 4) {
        float* b = buf[wave];
#pragma unroll
        for (int c = 0; c < 4; ++c)
#pragma unroll
            for (int r = 0; r < 16; ++r) {
                const int i2 = (c * 16 + r) * 64 + lane;
                b[i2] += accs[c][r];
            }
    }
    __syncthreads();

    const int t = threadIdx.x;
    const int c = t >> 7;
    const int r = (t >> 3) & 15;
    const int l0 = (t & 7) * 8;
    const int base = (c * 16 + r) * 64 + l0;
    float4 s0 = {0.f, 0.f, 0.f, 0.f}, s1 = {0.f, 0.f, 0.f, 0.f};
#pragma unroll
    for (int w = 0; w < 4; ++w) {
        const float4* p = (const float4*)&buf[w][base];
        float4 v0 = p[0], v1 = p[1];
        s0.x += v0.x; s0.y += v0.y; s0.z += v0.z; s0.w += v0.w;
        s1.x += v1.x; s1.y += v1.y; s1.z += v1.z; s1.w += v1.w;
    }
    alignas(16) float v[8] = {s0.x, s0.y, s0.z, s0.w, s1.x, s1.y, s1.z, s1.w};
    const int ih = c >> 1, jh = c & 1;
    const int row = ih * 32 + (r & 3) + 8 * (r >> 2) + 4 * (l0 >> 5);
    const int col0 = jh * 32 + (l0 & 31);
    const int m = mt * 64 + row;
    const int nl = (nt - 48) * 64 + col0;        // 0..1023 (O-local)
    float* p = P + ((size_t)ks << 18) + (size_t)m * 1024 + nl;
    *(float4*)p = *(const float4*)&v[0];
    *(float4*)(p + 4) = *(const float4*)&v[4];
}

// ---- t=9 reduce: h10_O = relu(sum_ks P[ks]) -> bf16 swizzled frags ----
__global__ __launch_bounds__(256) void k_red9(const float* __restrict__ P,
                                              __bf16* __restrict__ hn) {
    const int g = blockIdx.x * 256 + threadIdx.x;   // 0..32767
    const int m = g >> 7;
    const int n8 = (g & 127) << 3;
    const float* p = P + (size_t)m * 1024 + n8;
    float4 a0 = *(const float4*)p, a1 = *(const float4*)(p + 4);
#pragma unroll
    for (int ks = 1; ks < 4; ++ks) {
        const float* q = p + ((size_t)ks << 18);
        float4 b0 = *(const float4*)q, b1 = *(const float4*)(q + 4);
        a0.x += b0.x; a0.y += b0.y; a0.z += b0.z; a0.w += b0.w;
        a1.x += b1.x; a1.y += b1.y; a1.z += b1.z; a1.w += b1.w;
    }
    alignas(16) __bf16 o[8];
    o[0] = (__bf16)fmaxf(a0.x, 0.f); o[1] = (__bf16)fmaxf(a0.y, 0.f);
    o[2] = (__bf16)fmaxf(a0.z, 0.f); o[3] = (__bf16)fmaxf(a0.w, 0.f);
    o[4] = (__bf16)fmaxf(a1.x, 0.f); o[5] = (__bf16)fmaxf(a1.y, 0.f);
    o[6] = (__bf16)fmaxf(a1.z, 0.f); o[7] = (__bf16)fmaxf(a1.w, 0.f);
    const int n0g = 3072 + n8;
    const size_t frag = (size_t)(m >> 5) * (TOTAL / 16) + (n0g >> 4);
    const int lh = (m & 31) + 32 * ((n0g >> 3) & 1);
    *(ulonglong2*)(hn + frag * 512 + lh * 8) = *(const ulonglong2*)o;
}

// ---- out = h[:, 3072:] @ out_w^T + out_b (h tiled, out_w tiled padded to 1024 rows) ----
__global__ __launch_bounds__(512, 4) void k_out(const __bf16* __restrict__ h,
                                                const __bf16* __restrict__ owt,
                                                const float* __restrict__ out_b,
                                                float* __restrict__ out) {
    __shared__ float red[8][1024];
    const int wave = threadIdx.x >> 6;
    const int lane = threadIdx.x & 63;
    const int mt = blockIdx.x >> 5;
    const int ct = blockIdx.x & 31;
    const int m0 = mt * 32, c0 = ct * 32;
    const int kcA0 = (3072 / 16) + wave * 8;
    const int kcB0 = wave * 8;
    const bf16x8* Ap = (const bf16x8*)h   + ((size_t)mt * (TOTAL / 16) + kcA0) * 64 + lane;
    const bf16x8* Bp = (const bf16x8*)owt + ((size_t)ct * (1024 / 16) + kcB0) * 64 + lane;
    f32x16 acc = zero16();
#pragma unroll
    for (int i = 0; i < 8; ++i)
        acc = MFMA(Ap[i * 64], Bp[i * 64], acc);
#pragma unroll
    for (int r = 0; r < 16; ++r) {
        int row = (r & 3) + 8 * (r >> 2) + 4 * (lane >> 5);
        red[wave][row * 32 + (lane & 31)] = acc[r];
    }
    __syncthreads();
    const int e0 = threadIdx.x * 2;
    float sx = 0.f, sy = 0.f;
#pragma unroll
    for (int w = 0; w < 8; ++w) {
        float2 v = *(const float2*)&red[w][e0];
        sx += v.x; sy += v.y;
    }
    const int row = e0 >> 5, col = e0 & 31;
    const int m = m0 + row;
    const int n = c0 + col;
    if (n < NCLS)     out[m * NCLS + n]     = sx + out_b[n];
    if (n + 1 < NCLS) out[m * NCLS + n + 1] = sy + out_b[n + 1];
}

extern "C" void kernel_launch(void* const* d_in, const int* in_sizes, int n_in,
                              void* d_out, int out_size, void* d_ws, size_t ws_size,
                              hipStream_t stream) {
    const float* x     = (const float*)d_in[0];   // 256 x 2048
    const float* W     = (const float*)d_in[1];   // 4096 x 4096
    const float* in_w  = (const float*)d_in[2];   // 1024 x 2048
    const float* in_b  = (const float*)d_in[3];   // 1024
    const float* out_w = (const float*)d_in[4];   // 1000 x 1024
    const float* out_b = (const float*)d_in[5];   // 1000
    float* out = (float*)d_out;                   // 256 x 1000

    char* ws = (char*)d_ws;
    __bf16* WT  = (__bf16*)(ws + 0);          // 32 MiB  W^T tiled (r=n, c=k)
    __bf16* OWT = (__bf16*)(ws + 33554432);   // 2 MiB   out_w tiled (padded 1024 rows)
    float*  Ebuf= (float*)(ws + 35651584);    // 1 MiB   E f32 row-major
    __bf16* H0  = (__bf16*)(ws + 36700160);   // 2 MiB   h tiled
    __bf16* H1  = (__bf16*)(ws + 38797312);   // 2 MiB   h tiled
    float*  Pbuf= (float*)(ws + 40894464);    // 32 MiB  f32 partials (8 x 256 x 4096)

    // prep: E-GEMM (writes Ebuf + H0 relu'd) + W transpose-swizzle + out_w swizzle.
    // t=0 collapses to h1 = [relu(E),0,0]; step t=1 reads only K<1024 so H0's upper
    // region needs no memset.
    k_prep<<<2816, 256, 0, stream>>>(W, x, in_w, in_b, out_w, WT, OWT, Ebuf, H0);

    const __bf16* hs = H0;
    __bf16* hd = H1;

    // t=1: K=1024 only (h1 = [relu(E),0,0]); gate=0
    k_step3<SDIM / 16><<<256, 1024, 0, stream>>>(hs, WT, Ebuf, 0, hd);
    { const __bf16* tmp = hs; hs = hd; hd = (__bf16*)tmp; }

    // t=2..8 full steps: T4-pipelined LDS-staged 128x128 k-split-8 + 8-slice reduce
    for (int t = 2; t < 9; ++t) {
        k_stepP<<<512, 512, 0, stream>>>(hs, WT, Pbuf);
        k_red8<<<512, 256, 0, stream>>>(Pbuf, Ebuf, (t % 5 == 0) ? 1 : 0, hd);
        const __bf16* tmp = hs; hs = hd; hd = (__bf16*)tmp;
    }

    // t=9: only the O-panel feeds k_out -> 1/4 work, k-split x4 + reduce
    k_part9<<<256, 512, 0, stream>>>(hs, WT, Pbuf);
    k_red9<<<128, 256, 0, stream>>>(Pbuf, hd);

    k_out<<<256, 512, 0, stream>>>(hd, OWT, out_b, out);
}

// Round 10
// 255.790 us; speedup vs baseline: 1.3592x; 1.2695x over previous
//
#include <hip/hip_runtime.h>

// BasicRNN R20: revert steps to R14 permanently (R19's T4 counted-vmcnt ran same
// ~30us as R16's drain-0 -> gload_lds has intrinsic ~2x/instr cost on 1KB-frag
// patterns; 5 structural step rewrites all lost to direct-load). Step floor is
// structural: M=256 evenly over 256 CUs = 64x64 output/CU -> 1MB operand/CU at
// the measured ~17 B/cyc delivery = 26us/step. R12/R14 sit at the layout optimum.
// THIS ROUND: k_prep (40us @ 27% HBM, VALUBusy 6%, Occ 28%, 0 bank conflicts =
// latency/concurrency-bound; traffic floor ~16us). W-phase tiles 16k x 512n ->
// 16k x 256n: 4096 blocks, 16KB LDS -> 8 blocks/CU resident (2x waves in flight).
// Emit gather stays conflict-free (bank = lane&31). All else identical to R14
// (257.6us measured). Predict prep 40->~30, total ~248.
// FALSIFIER: prep >= 38us -> ds/instr-rate bound -> declare roofline ~258.
// Fragment-tiled operands:
//   elem(r,c) = frag*512 + lane*8 + (c&7), frag=(r>>5)*(C/16)+(c>>4), lane=(r&31)+32*((c>>3)&1)

typedef __bf16 bf16x8 __attribute__((ext_vector_type(8)));
typedef float  f32x16 __attribute__((ext_vector_type(16)));

#define TOTAL 4096
#define BATCH 256
#define INDIM 2048
#define SDIM  1024
#define NCLS  1000

#define MFMA(a, b, c) __builtin_amdgcn_mfma_f32_32x32x16_bf16((a), (b), (c), 0, 0, 0)

__device__ inline f32x16 zero16() {
    f32x16 v;
#pragma unroll
    for (int i = 0; i < 16; ++i) v[i] = 0.f;
    return v;
}

__device__ inline void swz_slot(const float* __restrict__ in, __bf16* __restrict__ out,
                                int C, int Rvalid, int t) {
    const int lane = t & 63;
    const int frag = t >> 6;
    const int kcN = C >> 4;
    const int rt = frag / kcN;
    const int kc = frag - rt * kcN;
    const int r = rt * 32 + (lane & 31);
    const int c = kc * 16 + (lane >> 5) * 8;
    alignas(16) __bf16 v[8];
    if (r < Rvalid) {
        const float* p = in + (size_t)r * C + c;
#pragma unroll
        for (int j = 0; j < 8; ++j) v[j] = (__bf16)p[j];
    } else {
#pragma unroll
        for (int j = 0; j < 8; ++j) v[j] = (__bf16)0.f;
    }
    *(ulonglong2*)(out + (size_t)t * 8) = *(const ulonglong2*)v;
}

// ---- merged preprocessing + E-GEMM ----
// grid 4864 x 256: [0,256) E-GEMM; [256,4352) W transpose-swizzle (16k x 256n tiles,
// 16KB LDS -> 8 blocks/CU); [4352,4864) out_w swizzle
__global__ __launch_bounds__(256) void k_prep(const float* __restrict__ W,
                                              const float* __restrict__ x,
                                              const float* __restrict__ in_w,
                                              const float* __restrict__ in_b,
                                              const float* __restrict__ out_w,
                                              __bf16* __restrict__ WT,
                                              __bf16* __restrict__ OWT,
                                              float* __restrict__ Ebuf,
                                              __bf16* __restrict__ H0) {
    __shared__ float t[16 * 256];   // 16 KB; E path reuses as 4x1024 reduce buf
    const int bid = blockIdx.x;
    const int tid = threadIdx.x;
    if (bid < 256) {
        // ---- E = x @ in_w^T + in_b ; H0[:, :1024] = relu(E) (tiled) ----
        float* red = t;   // 4 x 1024 = 16 KB (exact fit)
        const int mt = bid >> 5, nt = bid & 31;
        const int wave = tid >> 6, lane = tid & 63;
        const int l31 = lane & 31, kh = (lane >> 5) * 8;
        const int k0 = wave * 512;
        const float* Ax = x    + (size_t)(mt * 32 + l31) * INDIM + k0 + kh;
        const float* Bw = in_w + (size_t)(nt * 32 + l31) * INDIM + k0 + kh;
        f32x16 acc = zero16();
#pragma unroll 4
        for (int i = 0; i < 32; ++i) {
            const float* pa = Ax + i * 16;
            const float* pb = Bw + i * 16;
            float4 a0 = *(const float4*)pa, a1 = *(const float4*)(pa + 4);
            float4 b0 = *(const float4*)pb, b1 = *(const float4*)(pb + 4);
            bf16x8 a, b;
            a[0] = (__bf16)a0.x; a[1] = (__bf16)a0.y; a[2] = (__bf16)a0.z; a[3] = (__bf16)a0.w;
            a[4] = (__bf16)a1.x; a[5] = (__bf16)a1.y; a[6] = (__bf16)a1.z; a[7] = (__bf16)a1.w;
            b[0] = (__bf16)b0.x; b[1] = (__bf16)b0.y; b[2] = (__bf16)b0.z; b[3] = (__bf16)b0.w;
            b[4] = (__bf16)b1.x; b[5] = (__bf16)b1.y; b[6] = (__bf16)b1.z; b[7] = (__bf16)b1.w;
            acc = MFMA(a, b, acc);
        }
#pragma unroll
        for (int r = 0; r < 16; ++r) {
            int row = (r & 3) + 8 * (r >> 2) + 4 * (lane >> 5);
            red[wave * 1024 + row * 32 + l31] = acc[r];
        }
        __syncthreads();
        const int e0 = tid * 4;
        float4 s = {0.f, 0.f, 0.f, 0.f};
#pragma unroll
        for (int w = 0; w < 4; ++w) {
            float4 v = *(const float4*)&red[w * 1024 + e0];
            s.x += v.x; s.y += v.y; s.z += v.z; s.w += v.w;
        }
        const int row = e0 >> 5, col = e0 & 31;
        const int m = mt * 32 + row, n = nt * 32 + col;
        float v[4] = {s.x + in_b[n], s.y + in_b[n + 1], s.z + in_b[n + 2], s.w + in_b[n + 3]};
        *(float4*)(Ebuf + m * SDIM + n) = *(const float4*)v;
        alignas(8) __bf16 o[4];
#pragma unroll
        for (int j = 0; j < 4; ++j) o[j] = (__bf16)fmaxf(v[j], 0.f);
        const size_t frag = (size_t)(m >> 5) * (TOTAL / 16) + (n >> 4);
        const int lh = (m & 31) + 32 * ((n >> 3) & 1);
        *(ushort4*)(H0 + frag * 512 + lh * 8 + (n & 7)) = *(const ushort4*)o;
    } else if (bid < 4352) {
        // ---- W (f32, W[k][n]) -> WT tiled bf16 (r=n, c=k); 16k x 256n tile ----
        const int wb = bid - 256;
        const int k0 = (wb >> 4) * 16;     // 256 k-tiles
        const int n0 = (wb & 15) * 256;    // 16 n-panels
        // stage: 16 rows x 1KB contiguous reads -> t[k][n] (16x256 f32), float4 writes
#pragma unroll
        for (int i = 0; i < 4; ++i) {
            const int slot = i * 256 + tid;        // 1024 float4 slots
            const int row = slot >> 6;             // 64 float4 per row
            const int c4 = (slot & 63) * 4;
            float4 v = *(const float4*)(W + (size_t)(k0 + row) * TOTAL + n0 + c4);
            *(float4*)&t[row * 256 + c4] = v;
        }
        __syncthreads();
        // emit: 8 frags (rtl 0..7) at fixed kc; 8x ds_read_b32 column gather
        // (bank = lane&31 -> conflict-free, 2-way alias free)
        const int kcG = k0 >> 4;
#pragma unroll
        for (int s = tid; s < 512; s += 256) {
            const int rtl = s >> 6;
            const int lane = s & 63;
            const int nl = rtl * 32 + (lane & 31);
            const int kl = (lane >> 5) * 8;
            bf16x8 v;
#pragma unroll
            for (int j = 0; j < 8; ++j) v[j] = (__bf16)t[(kl + j) * 256 + nl];
            const size_t fragG = (size_t)((n0 >> 5) + rtl) * (TOTAL / 16) + kcG;
            *(bf16x8*)(WT + fragG * 512 + lane * 8) = v;
        }
    } else {
        swz_slot(out_w, OWT, 1024, NCLS, (bid - 4352) * 256 + tid);
    }
}

// ---- one recurrence step: hn = relu(h @ W + gate*[E,0,0]) (h, hn, WT tiled) ----
// 256 blocks x 1024 thr (16 waves = 4/SIMD); block tile 64m x 64n; K-split 16.
// No barriers in the K-loop (direct L2/L3 loads). Reduce: phase1 waves 8..15 store
// to buf[w-8], phase2 waves 0..7 add, final 8-way sum + epilogue.
// XCD-aware bid swizzle: all 4 mt of an nt-panel on one XCD (bid%8 ~ XCD id).
template <int CHUNKS>
__global__ __launch_bounds__(1024, 1) void k_step3(const __bf16* __restrict__ h,
                                                   const __bf16* __restrict__ WT,
                                                   const float* __restrict__ E,
                                                   const int gate,
                                                   __bf16* __restrict__ hn) {
    __shared__ float buf[8][4096];   // 128 KiB -> 1 block/CU
    const int w = threadIdx.x >> 6;
    const int lane = threadIdx.x & 63;
    const int xcd = blockIdx.x & 7;
    const int idx = blockIdx.x >> 3;       // 0..31
    const int mt = idx & 3;                // m0 = mt*64
    const int nt = xcd * 8 + (idx >> 2);   // 0..63
    constexpr int PER = CHUNKS >> 4;       // 16-way K-split
    const int kc0 = w * PER;

    const bf16x8* A0 = (const bf16x8*)h  + ((size_t)(mt * 2) * (TOTAL / 16) + kc0) * 64 + lane;
    const bf16x8* A1 = A0 + (size_t)(TOTAL / 16) * 64;
    const bf16x8* B0 = (const bf16x8*)WT + ((size_t)(nt * 2) * (TOTAL / 16) + kc0) * 64 + lane;
    const bf16x8* B1 = B0 + (size_t)(TOTAL / 16) * 64;

    f32x16 ac0 = zero16(), ac1 = zero16(), ac2 = zero16(), ac3 = zero16();
#pragma unroll 4
    for (int i = 0; i < PER; ++i) {
        const int off = i * 64;
        bf16x8 a0 = A0[off];
        bf16x8 a1 = A1[off];
        bf16x8 b0 = B0[off];
        bf16x8 b1 = B1[off];
        ac0 = MFMA(a0, b0, ac0);
        ac1 = MFMA(a0, b1, ac1);
        ac2 = MFMA(a1, b0, ac2);
        ac3 = MFMA(a1, b1, ac3);
    }

    // reduce: idx(c,r,l) = (c*16+r)*64 + l (2-way bank alias: free)
    f32x16 accs[4] = {ac0, ac1, ac2, ac3};
    if (w >= 8) {
        float* b = buf[w - 8];
#pragma unroll
        for (int cc = 0; cc < 4; ++cc)
#pragma unroll
            for (int rr = 0; rr < 16; ++rr)
                b[(cc * 16 + rr) * 64 + lane] = accs[cc][rr];
    }
    __syncthreads();
    if (w < 8) {
        float* b = buf[w];
#pragma unroll
        for (int cc = 0; cc < 4; ++cc)
#pragma unroll
            for (int rr = 0; rr < 16; ++rr) {
                const int i2 = (cc * 16 + rr) * 64 + lane;
                b[i2] += accs[cc][rr];
            }
    }
    __syncthreads();

    // final 8-way sum + epilogue; thread t -> (c, r, 4 lanes from l0)
    const int t = threadIdx.x;
    const int c = t >> 8;            // 0..3
    const int r = (t >> 4) & 15;     // 0..15
    const int l0 = (t & 15) * 4;     // 0..60
    const int base = (c * 16 + r) * 64 + l0;
    float4 s = {0.f, 0.f, 0.f, 0.f};
#pragma unroll
    for (int wb = 0; wb < 8; ++wb) {
        float4 v0 = *(const float4*)&buf[wb][base];
        s.x += v0.x; s.y += v0.y; s.z += v0.z; s.w += v0.w;
    }
    float v[4] = {s.x, s.y, s.z, s.w};
    const int ih = c >> 1, jh = c & 1;
    const int row = ih * 32 + (r & 3) + 8 * (r >> 2) + 4 * (l0 >> 5);
    const int col0 = jh * 32 + (l0 & 31);
    const int m = mt * 64 + row;
    const int n0g = nt * 64 + col0;
    if (gate && n0g < SDIM) {
        const float* Ep = E + m * SDIM + n0g;
#pragma unroll
        for (int j = 0; j < 4; ++j) v[j] += Ep[j];
    }
    alignas(8) __bf16 o[4];
#pragma unroll
    for (int j = 0; j < 4; ++j) o[j] = (__bf16)fmaxf(v[j], 0.f);
    const size_t frag = (size_t)(m >> 5) * (TOTAL / 16) + (n0g >> 4);
    const int lh = (m & 31) + 32 * ((n0g >> 3) & 1);
    *(ushort4*)(hn + frag * 512 + lh * 8 + (n0g & 7)) = *(const ushort4*)o;
}

// ---- t=9 partial: P[ks] = h9 @ W[kslice, 3072:4096] (no relu, no gate) ----
// 256 blocks x 512 thr: 16 nt-panels (O block) x 4 mt x 4 k-split; 8 waves split
// each 1024-k slice. Per-XCD footprint: 2 WT panels (1MB) + h (2MB) = 3MB <= L2.
__global__ __launch_bounds__(512, 2) void k_part9(const __bf16* __restrict__ h,
                                                  const __bf16* __restrict__ WT,
                                                  float* __restrict__ P) {
    __shared__ float buf[4][4096];
    const int wave = threadIdx.x >> 6;
    const int lane = threadIdx.x & 63;
    const int xcd = blockIdx.x & 7;
    const int idx = blockIdx.x >> 3;             // 0..31
    const int nt = 48 + xcd * 2 + (idx >> 4);    // 48..63 (O panel)
    const int mt = (idx >> 2) & 3;
    const int ks = idx & 3;
    const int kc0 = ks * 64 + wave * 8;          // 8 chunks/wave = 128 k

    const bf16x8* A0 = (const bf16x8*)h  + ((size_t)(mt * 2) * (TOTAL / 16) + kc0) * 64 + lane;
    const bf16x8* A1 = A0 + (size_t)(TOTAL / 16) * 64;
    const bf16x8* B0 = (const bf16x8*)WT + ((size_t)(nt * 2) * (TOTAL / 16) + kc0) * 64 + lane;
    const bf16x8* B1 = B0 + (size_t)(TOTAL / 16) * 64;

    f32x16 ac0 = zero16(), ac1 = zero16(), ac2 = zero16(), ac3 = zero16();
#pragma unroll 4
    for (int i = 0; i < 8; ++i) {
        const int off = i * 64;
        bf16x8 a0 = A0[off];
        bf16x8 a1 = A1[off];
        bf16x8 b0 = B0[off];
        bf16x8 b1 = B1[off];
        ac0 = MFMA(a0, b0, ac0);
        ac1 = MFMA(a0, b1, ac1);
        ac2 = MFMA(a1, b0, ac2);
        ac3 = MFMA(a1, b1, ac3);
    }

    f32x16 accs[4] = {ac0, ac1, ac2, ac3};
    if (wave >= 4) {
        float* b = buf[wave - 4];
#pragma unroll
        for (int c = 0; c < 4; ++c)
#pragma unroll
            for (int r = 0; r < 16; ++r)
                b[(c * 16 + r) * 64 + lane] = accs[c][r];
    }
    __syncthreads();
    if (wave < 4) {
        float* b = buf[wave];
#pragma unroll
        for (int c = 0; c < 4; ++c)
#pragma unroll
            for (int r = 0; r < 16; ++r) {
                const int i2 = (c * 16 + r) * 64 + lane;
                b[i2] += accs[c][r];
            }
    }
    __syncthreads();

    const int t = threadIdx.x;
    const int c = t >> 7;
    const int r = (t >> 3) & 15;
    const int l0 = (t & 7) * 8;
    const int base = (c * 16 + r) * 64 + l0;
    float4 s0 = {0.f, 0.f, 0.f, 0.f}, s1 = {0.f, 0.f, 0.f, 0.f};
#pragma unroll
    for (int w = 0; w < 4; ++w) {
        const float4* p = (const float4*)&buf[w][base];
        float4 v0 = p[0], v1 = p[1];
        s0.x += v0.x; s0.y += v0.y; s0.z += v0.z; s0.w += v0.w;
        s1.x += v1.x; s1.y += v1.y; s1.z += v1.z; s1.w += v1.w;
    }
    alignas(16) float v[8] = {s0.x, s0.y, s0.z, s0.w, s1.x, s1.y, s1.z, s1.w};
    const int ih = c >> 1, jh = c & 1;
    const int row = ih * 32 + (r & 3) + 8 * (r >> 2) + 4 * (l0 >> 5);
    const int col0 = jh * 32 + (l0 & 31);
    const int m = mt * 64 + row;
    const int nl = (nt - 48) * 64 + col0;        // 0..1023 (O-local)
    float* p = P + ((size_t)ks << 18) + (size_t)m * 1024 + nl;
    *(float4*)p = *(const float4*)&v[0];
    *(float4*)(p + 4) = *(const float4*)&v[4];
}

// ---- t=9 reduce: h10_O = relu(sum_ks P[ks]) -> bf16 swizzled frags ----
__global__ __launch_bounds__(256) void k_red9(const float* __restrict__ P,
                                              __bf16* __restrict__ hn) {
    const int g = blockIdx.x * 256 + threadIdx.x;   // 0..32767
    const int m = g >> 7;
    const int n8 = (g & 127) << 3;
    const float* p = P + (size_t)m * 1024 + n8;
    float4 a0 = *(const float4*)p, a1 = *(const float4*)(p + 4);
#pragma unroll
    for (int ks = 1; ks < 4; ++ks) {
        const float* q = p + ((size_t)ks << 18);
        float4 b0 = *(const float4*)q, b1 = *(const float4*)(q + 4);
        a0.x += b0.x; a0.y += b0.y; a0.z += b0.z; a0.w += b0.w;
        a1.x += b1.x; a1.y += b1.y; a1.z += b1.z; a1.w += b1.w;
    }
    alignas(16) __bf16 o[8];
    o[0] = (__bf16)fmaxf(a0.x, 0.f); o[1] = (__bf16)fmaxf(a0.y, 0.f);
    o[2] = (__bf16)fmaxf(a0.z, 0.f); o[3] = (__bf16)fmaxf(a0.w, 0.f);
    o[4] = (__bf16)fmaxf(a1.x, 0.f); o[5] = (__bf16)fmaxf(a1.y, 0.f);
    o[6] = (__bf16)fmaxf(a1.z, 0.f); o[7] = (__bf16)fmaxf(a1.w, 0.f);
    const int n0g = 3072 + n8;
    const size_t frag = (size_t)(m >> 5) * (TOTAL / 16) + (n0g >> 4);
    const int lh = (m & 31) + 32 * ((n0g >> 3) & 1);
    *(ulonglong2*)(hn + frag * 512 + lh * 8) = *(const ulonglong2*)o;
}

// ---- out = h[:, 3072:] @ out_w^T + out_b (h tiled, out_w tiled padded to 1024 rows) ----
__global__ __launch_bounds__(512, 4) void k_out(const __bf16* __restrict__ h,
                                                const __bf16* __restrict__ owt,
                                                const float* __restrict__ out_b,
                                                float* __restrict__ out) {
    __shared__ float red[8][1024];
    const int wave = threadIdx.x >> 6;
    const int lane = threadIdx.x & 63;
    const int mt = blockIdx.x >> 5;
    const int ct = blockIdx.x & 31;
    const int m0 = mt * 32, c0 = ct * 32;
    const int kcA0 = (3072 / 16) + wave * 8;
    const int kcB0 = wave * 8;
    const bf16x8* Ap = (const bf16x8*)h   + ((size_t)mt * (TOTAL / 16) + kcA0) * 64 + lane;
    const bf16x8* Bp = (const bf16x8*)owt + ((size_t)ct * (1024 / 16) + kcB0) * 64 + lane;
    f32x16 acc = zero16();
#pragma unroll
    for (int i = 0; i < 8; ++i)
        acc = MFMA(Ap[i * 64], Bp[i * 64], acc);
#pragma unroll
    for (int r = 0; r < 16; ++r) {
        int row = (r & 3) + 8 * (r >> 2) + 4 * (lane >> 5);
        red[wave][row * 32 + (lane & 31)] = acc[r];
    }
    __syncthreads();
    const int e0 = threadIdx.x * 2;
    float sx = 0.f, sy = 0.f;
#pragma unroll
    for (int w = 0; w < 8; ++w) {
        float2 v = *(const float2*)&red[w][e0];
        sx += v.x; sy += v.y;
    }
    const int row = e0 >> 5, col = e0 & 31;
    const int m = m0 + row;
    const int n = c0 + col;
    if (n < NCLS)     out[m * NCLS + n]     = sx + out_b[n];
    if (n + 1 < NCLS) out[m * NCLS + n + 1] = sy + out_b[n + 1];
}

extern "C" void kernel_launch(void* const* d_in, const int* in_sizes, int n_in,
                              void* d_out, int out_size, void* d_ws, size_t ws_size,
                              hipStream_t stream) {
    const float* x     = (const float*)d_in[0];   // 256 x 2048
    const float* W     = (const float*)d_in[1];   // 4096 x 4096
    const float* in_w  = (const float*)d_in[2];   // 1024 x 2048
    const float* in_b  = (const float*)d_in[3];   // 1024
    const float* out_w = (const float*)d_in[4];   // 1000 x 1024
    const float* out_b = (const float*)d_in[5];   // 1000
    float* out = (float*)d_out;                   // 256 x 1000

    char* ws = (char*)d_ws;
    __bf16* WT  = (__bf16*)(ws + 0);          // 32 MiB  W^T tiled (r=n, c=k)
    __bf16* OWT = (__bf16*)(ws + 33554432);   // 2 MiB   out_w tiled (padded 1024 rows)
    float*  Ebuf= (float*)(ws + 35651584);    // 1 MiB   E f32 row-major
    __bf16* H0  = (__bf16*)(ws + 36700160);   // 2 MiB   h tiled
    __bf16* H1  = (__bf16*)(ws + 38797312);   // 2 MiB   h tiled
    float*  Pbuf= (float*)(ws + 40894464);    // 4 MiB   t=9 f32 partials (4 x 256 x 1024)

    // prep: E-GEMM (writes Ebuf + H0 relu'd) + W transpose-swizzle + out_w swizzle.
    // t=0 collapses to h1 = [relu(E),0,0]; step t=1 reads only K<1024 so H0's upper
    // region needs no memset.
    k_prep<<<4864, 256, 0, stream>>>(W, x, in_w, in_b, out_w, WT, OWT, Ebuf, H0);

    // t = 1..8 (gate fires at t=5); t=1 only needs K=1024. h9 ends in H0.
    const __bf16* hs = H0;
    __bf16* hd = H1;
    for (int t = 1; t < 9; ++t) {
        const int gate = (t % 5 == 0) ? 1 : 0;
        if (t == 1)
            k_step3<SDIM / 16><<<256, 1024, 0, stream>>>(hs, WT, Ebuf, gate, hd);
        else
            k_step3<TOTAL / 16><<<256, 1024, 0, stream>>>(hs, WT, Ebuf, gate, hd);
        const __bf16* tmp = hs; hs = hd; hd = (__bf16*)tmp;
    }

    // t=9: only the O-panel feeds k_out -> 1/4 work, k-split x4 + reduce
    k_part9<<<256, 512, 0, stream>>>(hs, WT, Pbuf);
    k_red9<<<128, 256, 0, stream>>>(Pbuf, hd);

    k_out<<<256, 512, 0, stream>>>(hd, OWT, out_b, out);
}